// Round 2
// baseline (514.437 us; speedup 1.0000x reference)
//
#include <hip/hip_runtime.h>

// MPS layer: 256 chains (batch=128 x half=2), each = ordered product of 32
// site matrices (128x128 f32), then out[b,c] = sum_{j,k} mid[c,j,k] * (R@L)[k,j].
//
// Round 1: resubmission of round-0 fp32 baseline (round-1 bench was an
// infra failure, no kernel signal).
//   kernel 1: one WG per chain. LDS double buffer (acc A, site B), 16x16
//             threads x 8x8 reg tile, float4 LDS loads. A rows interleaved
//             (r = ty + 16*i) for conflict-free A reads.
//   kernel 2: one WG per batch: P = R@L in LDS, contract with middle, reduce.
// Workspace: res[2][128][128][128] f32 = 16 MB in d_ws.

#define TS 132  // padded LDS row stride (floats); multiple of 4 keeps float4 alignment

__global__ __launch_bounds__(256) void mps_chain(const float* __restrict__ inp,
                                                 const float* __restrict__ left,
                                                 const float* __restrict__ right,
                                                 float* __restrict__ res) {
    __shared__ float lA[128 * TS];
    __shared__ float lB[128 * TS];
    __shared__ float xs[64];

    const int tid  = threadIdx.x;
    const int half = blockIdx.x >> 7;
    const int b    = blockIdx.x & 127;
    const float* __restrict__ W = half ? right : left;

    // inputs[b][site][s]: sites half*32..+32, flat = b*128 + half*64 + (0..63)
    if (tid < 64) xs[tid] = inp[b * 128 + half * 64 + tid];

    const int ty = tid >> 4, tx = tid & 15;
    const int c0 = tx * 8;

    __syncthreads();

    // A = M_0 = x0*W[0][0] + x1*W[1][0]
    {
        const float x0 = xs[0], x1 = xs[1];
        const float* W0 = W;
        const float* W1 = W + 32 * 16384;
#pragma unroll
        for (int it = 0; it < 16; ++it) {
            int g = it * 256 + tid;
            float4 w0 = *(const float4*)(W0 + g * 4);
            float4 w1 = *(const float4*)(W1 + g * 4);
            int row = g >> 5, col = (g & 31) * 4;
            float4 v = make_float4(x0 * w0.x + x1 * w1.x, x0 * w0.y + x1 * w1.y,
                                   x0 * w0.z + x1 * w1.z, x0 * w0.w + x1 * w1.w);
            *(float4*)&lA[row * TS + col] = v;
        }
    }

    float ct[8][8];

    for (int s = 1; s < 32; ++s) {
        // build B = M_s
        const float x0 = xs[2 * s], x1 = xs[2 * s + 1];
        const float* W0 = W + s * 16384;
        const float* W1 = W + (32 + s) * 16384;
#pragma unroll
        for (int it = 0; it < 16; ++it) {
            int g = it * 256 + tid;
            float4 w0 = *(const float4*)(W0 + g * 4);
            float4 w1 = *(const float4*)(W1 + g * 4);
            int row = g >> 5, col = (g & 31) * 4;
            float4 v = make_float4(x0 * w0.x + x1 * w1.x, x0 * w0.y + x1 * w1.y,
                                   x0 * w0.z + x1 * w1.z, x0 * w0.w + x1 * w1.w);
            *(float4*)&lB[row * TS + col] = v;
        }
        __syncthreads();  // A (prev iter writes) + B ready

#pragma unroll
        for (int i = 0; i < 8; ++i)
#pragma unroll
            for (int j = 0; j < 8; ++j) ct[i][j] = 0.f;

        for (int k = 0; k < 128; k += 4) {
            float4 a[8];
#pragma unroll
            for (int i = 0; i < 8; ++i)
                a[i] = *(const float4*)&lA[(ty + 16 * i) * TS + k];
            float4 b0[4], b1[4];
#pragma unroll
            for (int kk = 0; kk < 4; ++kk) {
                b0[kk] = *(const float4*)&lB[(k + kk) * TS + c0];
                b1[kk] = *(const float4*)&lB[(k + kk) * TS + c0 + 4];
            }
#pragma unroll
            for (int i = 0; i < 8; ++i) {
                const float av[4] = {a[i].x, a[i].y, a[i].z, a[i].w};
#pragma unroll
                for (int kk = 0; kk < 4; ++kk) {
                    const float aa = av[kk];
                    ct[i][0] = fmaf(aa, b0[kk].x, ct[i][0]);
                    ct[i][1] = fmaf(aa, b0[kk].y, ct[i][1]);
                    ct[i][2] = fmaf(aa, b0[kk].z, ct[i][2]);
                    ct[i][3] = fmaf(aa, b0[kk].w, ct[i][3]);
                    ct[i][4] = fmaf(aa, b1[kk].x, ct[i][4]);
                    ct[i][5] = fmaf(aa, b1[kk].y, ct[i][5]);
                    ct[i][6] = fmaf(aa, b1[kk].z, ct[i][6]);
                    ct[i][7] = fmaf(aa, b1[kk].w, ct[i][7]);
                }
            }
        }
        __syncthreads();  // all reads of A and B complete

        if (s < 31) {
#pragma unroll
            for (int i = 0; i < 8; ++i) {
                int r = ty + 16 * i;
                *(float4*)&lA[r * TS + c0]     = make_float4(ct[i][0], ct[i][1], ct[i][2], ct[i][3]);
                *(float4*)&lA[r * TS + c0 + 4] = make_float4(ct[i][4], ct[i][5], ct[i][6], ct[i][7]);
            }
            // no sync needed: next iteration's __syncthreads (post B-build)
            // orders these writes before the next matmul's reads.
        }
    }

    // store final acc (still in registers) to res[half][b]
    float* O = res + (half * 128 + b) * 16384;
#pragma unroll
    for (int i = 0; i < 8; ++i) {
        int r = ty + 16 * i;
        *(float4*)(O + r * 128 + c0)     = make_float4(ct[i][0], ct[i][1], ct[i][2], ct[i][3]);
        *(float4*)(O + r * 128 + c0 + 4) = make_float4(ct[i][4], ct[i][5], ct[i][6], ct[i][7]);
    }
}

__global__ __launch_bounds__(256) void mps_final(const float* __restrict__ res,
                                                 const float* __restrict__ middle,
                                                 float* __restrict__ out) {
    __shared__ float lA[128 * TS];  // R = res[1][b]
    __shared__ float lB[128 * TS];  // L = res[0][b]
    __shared__ float red[4][10];

    const int tid = threadIdx.x;
    const int b   = blockIdx.x;
    const float* Rg = res + (128 + b) * 16384;
    const float* Lg = res + b * 16384;

#pragma unroll
    for (int it = 0; it < 16; ++it) {
        int g = it * 256 + tid;
        int row = g >> 5, col = (g & 31) * 4;
        *(float4*)&lA[row * TS + col] = *(const float4*)(Rg + g * 4);
        *(float4*)&lB[row * TS + col] = *(const float4*)(Lg + g * 4);
    }
    __syncthreads();

    const int ty = tid >> 4, tx = tid & 15;
    const int k0 = ty * 8, j0 = tx * 8;  // P tile: rows k (from R), cols j (from L)

    float ct[8][8];
#pragma unroll
    for (int i = 0; i < 8; ++i)
#pragma unroll
        for (int j = 0; j < 8; ++j) ct[i][j] = 0.f;

    for (int k = 0; k < 128; k += 4) {
        float4 a[8];
#pragma unroll
        for (int i = 0; i < 8; ++i)
            a[i] = *(const float4*)&lA[(k0 + i) * TS + k];
        float4 b0[4], b1[4];
#pragma unroll
        for (int kk = 0; kk < 4; ++kk) {
            b0[kk] = *(const float4*)&lB[(k + kk) * TS + j0];
            b1[kk] = *(const float4*)&lB[(k + kk) * TS + j0 + 4];
        }
#pragma unroll
        for (int i = 0; i < 8; ++i) {
            const float av[4] = {a[i].x, a[i].y, a[i].z, a[i].w};
#pragma unroll
            for (int kk = 0; kk < 4; ++kk) {
                const float aa = av[kk];
                ct[i][0] = fmaf(aa, b0[kk].x, ct[i][0]);
                ct[i][1] = fmaf(aa, b0[kk].y, ct[i][1]);
                ct[i][2] = fmaf(aa, b0[kk].z, ct[i][2]);
                ct[i][3] = fmaf(aa, b0[kk].w, ct[i][3]);
                ct[i][4] = fmaf(aa, b1[kk].x, ct[i][4]);
                ct[i][5] = fmaf(aa, b1[kk].y, ct[i][5]);
                ct[i][6] = fmaf(aa, b1[kk].z, ct[i][6]);
                ct[i][7] = fmaf(aa, b1[kk].w, ct[i][7]);
            }
        }
    }
    // ct[i][jj] = P[k0+i][j0+jj],  P = R@L
    // out[b,c] = sum_{j,k} mid[c][j][k] * P[k][j]
#pragma unroll
    for (int c = 0; c < 10; ++c) {
        const float* m = middle + c * 16384;
        float acc = 0.f;
#pragma unroll
        for (int jj = 0; jj < 8; ++jj) {
            const float* mr = m + (j0 + jj) * 128 + k0;
            float4 m0 = *(const float4*)(mr);
            float4 m1 = *(const float4*)(mr + 4);
            acc += m0.x * ct[0][jj] + m0.y * ct[1][jj] + m0.z * ct[2][jj] + m0.w * ct[3][jj];
            acc += m1.x * ct[4][jj] + m1.y * ct[5][jj] + m1.z * ct[6][jj] + m1.w * ct[7][jj];
        }
        float v = acc;
#pragma unroll
        for (int off = 32; off > 0; off >>= 1) v += __shfl_down(v, off);
        if ((tid & 63) == 0) red[tid >> 6][c] = v;
    }
    __syncthreads();
    if (tid < 10)
        out[b * 10 + tid] = red[0][tid] + red[1][tid] + red[2][tid] + red[3][tid];
}

extern "C" void kernel_launch(void* const* d_in, const int* in_sizes, int n_in,
                              void* d_out, int out_size, void* d_ws, size_t ws_size,
                              hipStream_t stream) {
    const float* inputs = (const float*)d_in[0];  // (128, 64, 2)
    const float* left   = (const float*)d_in[1];  // (2, 32, 128, 128)
    const float* right  = (const float*)d_in[2];  // (2, 32, 128, 128)
    const float* middle = (const float*)d_in[3];  // (10, 128, 128)
    float* out = (float*)d_out;                   // (128, 10)
    float* res = (float*)d_ws;                    // [2][128][128][128] f32 = 16 MB

    mps_chain<<<256, 256, 0, stream>>>(inputs, left, right, res);
    mps_final<<<128, 256, 0, stream>>>(res, middle, out);
}

// Round 3
// 225.564 us; speedup vs baseline: 2.2807x; 2.2807x over previous
//
#include <hip/hip_runtime.h>

// MPS layer, MFMA version.
// Math: per chain (batch b, half) the site matrix is
//   M_s = x0*W0[s] + x1*W1[s] = s01*I + x0*D0[s] + x1*D1[s],  D = W - I (exact),
// and we maintain T = (M_0 ... M_s)^T in MFMA accumulators:
//   T_new = M_s^T T = s01*T (exact fp32 VALU) + x0*D0^T*T + x1*D1^T*T (MFMA bf16).
// T (fp32) is split hi/lo bf16 each step -> per-step rel error ~3e-5 (safe).
//
// Layouts (v_mfma_f32_32x32x16_bf16, all verified mappings):
//   A-operand: lane holds row m=l&31, k = 8*(l>>5)+j (j=0..7)
//   B-operand: lane holds col n=l&31, k = 8*(l>>5)+j
//   C/D:       lane holds col  c=l&31, row = (reg&3)+8*(reg>>2)+4*(l>>5)
// acc->B-operand conversion: for k-half q of tile: swap(reg_{8q+r}, reg_{8q+4+r})
// via v_permlane32_swap_b32 (out0=[a.lo,b.lo], out1=[a.hi,b.hi]); afterwards
// slot 8q+j holds T[32t+16q+8*hi+j][col] = exactly the B-operand element j.
//
// ws: res[2][128][128][128] f32 (16MB) | Dt (4MB bf16, fragment-major deltas)
// Dt[(side*2+p)*32+s][ks][mt][l][j] = W[side][p][s][16ks+8(l>>5)+j][32mt+(l&31)] - I

typedef __attribute__((ext_vector_type(8))) short short8v;
typedef __attribute__((ext_vector_type(16))) float f32x16;

__device__ __forceinline__ unsigned cvt_pk_bf16(float lo, float hi) {
  unsigned r;
  asm("v_cvt_pk_bf16_f32 %0, %1, %2" : "=v"(r) : "v"(lo), "v"(hi));
  return r;
}

__global__ __launch_bounds__(256) void make_dt(const float* __restrict__ left,
                                               const float* __restrict__ right,
                                               ushort* __restrict__ Dt) {
  const int gid = blockIdx.x * 256 + threadIdx.x;  // [0, 262144)
  const int l   = gid & 63;
  const int mt  = (gid >> 6) & 3;
  const int ks  = (gid >> 8) & 7;
  const int mat = gid >> 11;       // side*64 + p*32 + s
  const int side = mat >> 6;
  const int ps   = mat & 63;       // p*32 + s
  const float* W = side ? right : left;
  const int m  = 32 * mt + (l & 31);
  const int kb = 16 * ks + 8 * (l >> 5);
  const float* src = W + (size_t)(ps * 128 + kb) * 128 + m;
  float v[8];
#pragma unroll
  for (int j = 0; j < 8; ++j) {
    float w = src[j * 128];
    v[j] = w - ((kb + j == m) ? 1.0f : 0.0f);
  }
  uint4 o;
  o.x = cvt_pk_bf16(v[0], v[1]);
  o.y = cvt_pk_bf16(v[2], v[3]);
  o.z = cvt_pk_bf16(v[4], v[5]);
  o.w = cvt_pk_bf16(v[6], v[7]);
  *(uint4*)(Dt + (size_t)gid * 8) = o;
}

__global__ __launch_bounds__(256, 1) void mps_chain_mfma(
    const float* __restrict__ inp, const float* __restrict__ left,
    const float* __restrict__ right, const ushort* __restrict__ Dt,
    float* __restrict__ res) {
  __shared__ ushort ldsD[2][32768];  // [buf][p*16384 + ((ks*4+mt)*64 + lane)*8]
  __shared__ float xs[64];

  const int tid  = threadIdx.x;
  const int half = blockIdx.x >> 7;
  const int b    = blockIdx.x & 127;
  const int lane = tid & 63;
  const int w    = tid >> 6;       // wave owns T cols 32w..32w+31
  const int c    = lane & 31;
  const int hi   = lane >> 5;
  const int cg   = 32 * w + c;

  if (tid < 64) xs[tid] = inp[b * 128 + half * 64 + tid];

  const ushort* DtH = Dt + (size_t)(half * 2) * 32 * 16384;  // p=0 slab base

  f32x16 acc[4];     // T_old: acc[t] = T rows 32t..32t+31, col cg
  short8v stg[2][8]; // staged next-step deltas (reg roundtrip, T14-style)

  // prefetch s=1 deltas into registers
#pragma unroll
  for (int p = 0; p < 2; ++p) {
    const ushort* sb = DtH + (size_t)(p * 32 + 1) * 16384;
#pragma unroll
    for (int i = 0; i < 8; ++i)
      stg[p][i] = *(const short8v*)(sb + (i * 256 + tid) * 8);
  }

  __syncthreads();  // xs ready

  // T_0 = M_0^T directly from W (fp32): T0[row][cg] = M0[cg][row]
  {
    const float* Wg = half ? right : left;
    const float x0 = xs[0], x1 = xs[1];
#pragma unroll
    for (int t = 0; t < 4; ++t)
#pragma unroll
      for (int g = 0; g < 4; ++g) {
        const int row = 32 * t + 8 * g + 4 * hi;  // regs 4g..4g+3 -> rows row..row+3
        const float4 w0 = *(const float4*)(Wg + cg * 128 + row);
        const float4 w1 = *(const float4*)(Wg + 32 * 16384 + cg * 128 + row);
        acc[t][4 * g + 0] = x0 * w0.x + x1 * w1.x;
        acc[t][4 * g + 1] = x0 * w0.y + x1 * w1.y;
        acc[t][4 * g + 2] = x0 * w0.z + x1 * w1.z;
        acc[t][4 * g + 3] = x0 * w0.w + x1 * w1.w;
      }
  }

  // write staged s=1 into buf 0
#pragma unroll
  for (int p = 0; p < 2; ++p)
#pragma unroll
    for (int i = 0; i < 8; ++i)
      *(short8v*)&ldsD[0][p * 16384 + i * 2048 + tid * 8] = stg[p][i];
  __syncthreads();

  int cur = 0;
  for (int s = 1; s < 32; ++s) {
    const float x0 = xs[2 * s], x1 = xs[2 * s + 1];
    const float s01 = x0 + x1;

    // issue prefetch of step s+1 (latency hides under convert+mfma)
    if (s < 31) {
#pragma unroll
      for (int p = 0; p < 2; ++p) {
        const ushort* sb = DtH + (size_t)(p * 32 + s + 1) * 16384;
#pragma unroll
        for (int i = 0; i < 8; ++i)
          stg[p][i] = *(const short8v*)(sb + (i * 256 + tid) * 8);
      }
    }

    // T_new := s01 * T_old (identity part, exact) BEFORE destroying acc
    f32x16 tn[4];
#pragma unroll
    for (int t = 0; t < 4; ++t)
#pragma unroll
      for (int r = 0; r < 16; ++r) tn[t][r] = s01 * acc[t][r];

    // convert T_old -> B-operand frags, scaled by x0 (sets 0,1) and x1 (2,3)
    short8v y[8][4];  // [ks][0]=x0*T hi, [1]=x0*T lo, [2]=x1*T hi, [3]=x1*T lo
#pragma unroll
    for (int t = 0; t < 4; ++t)
#pragma unroll
      for (int q = 0; q < 2; ++q) {
        const int ks = 2 * t + q;
#pragma unroll
        for (int r = 0; r < 4; ++r) {
          float a  = acc[t][q * 8 + r];
          float b2 = acc[t][q * 8 + 4 + r];
          asm volatile("v_permlane32_swap_b32 %0, %1" : "+v"(a), "+v"(b2));
          acc[t][q * 8 + r]     = a;   // = T[32t+16q+8*hi+r][cg]
          acc[t][q * 8 + 4 + r] = b2;  // = T[32t+16q+8*hi+4+r][cg]
        }
#pragma unroll
        for (int set = 0; set < 2; ++set) {
          const float sv = set ? x1 : x0;
          unsigned hw[4], lw[4];
#pragma unroll
          for (int pr = 0; pr < 4; ++pr) {  // element pairs (2pr, 2pr+1)
            float v0 = sv * acc[t][q * 8 + 2 * pr];
            float v1 = sv * acc[t][q * 8 + 2 * pr + 1];
            unsigned u0 = __builtin_bit_cast(unsigned, v0) & 0xffff0000u;
            unsigned u1 = __builtin_bit_cast(unsigned, v1) & 0xffff0000u;
            float l0 = v0 - __builtin_bit_cast(float, u0);  // exact residual
            float l1 = v1 - __builtin_bit_cast(float, u1);
            hw[pr] = (u0 >> 16) | u1;         // packed bf16 pair (hi parts)
            lw[pr] = cvt_pk_bf16(l0, l1);     // packed bf16 pair (lo parts)
          }
          uint4 ph = {hw[0], hw[1], hw[2], hw[3]};
          uint4 pl = {lw[0], lw[1], lw[2], lw[3]};
          y[ks][set * 2 + 0] = __builtin_bit_cast(short8v, ph);
          y[ks][set * 2 + 1] = __builtin_bit_cast(short8v, pl);
        }
      }

    // write staged s+1 to the other buffer (compiler inserts vmcnt wait)
    if (s < 31) {
#pragma unroll
      for (int p = 0; p < 2; ++p)
#pragma unroll
        for (int i = 0; i < 8; ++i)
          *(short8v*)&ldsD[cur ^ 1][p * 16384 + i * 2048 + tid * 8] = stg[p][i];
    }

    // MFMA: tn += x0*D0^T*T + x1*D1^T*T
#pragma unroll
    for (int ks = 0; ks < 8; ++ks) {
      short8v d0[4], d1[4];
#pragma unroll
      for (int mt = 0; mt < 4; ++mt) {
        d0[mt] = *(const short8v*)&ldsD[cur][(ks * 4 + mt) * 512 + lane * 8];
        d1[mt] = *(const short8v*)&ldsD[cur][16384 + (ks * 4 + mt) * 512 + lane * 8];
      }
#pragma unroll
      for (int pass = 0; pass < 4; ++pass) {
        const short8v* dd = (pass < 2) ? d0 : d1;
        const short8v yy = y[ks][pass];
#pragma unroll
        for (int mt = 0; mt < 4; ++mt)
          tn[mt] = __builtin_amdgcn_mfma_f32_32x32x16_bf16(dd[mt], yy, tn[mt], 0, 0, 0);
      }
    }

#pragma unroll
    for (int t = 0; t < 4; ++t) acc[t] = tn[t];
    __syncthreads();  // buf[cur] reads done by all; buf[cur^1] writes visible
    cur ^= 1;
  }

  // T[r][cg] = L[cg][r]: store row cg of L/R row-major (same ws layout as before)
  float* O = res + (size_t)(half * 128 + b) * 16384;
#pragma unroll
  for (int t = 0; t < 4; ++t)
#pragma unroll
    for (int g = 0; g < 4; ++g) {
      const int row = 32 * t + 8 * g + 4 * hi;
      float4 o = {acc[t][4 * g + 0], acc[t][4 * g + 1], acc[t][4 * g + 2], acc[t][4 * g + 3]};
      *(float4*)(O + cg * 128 + row) = o;
    }
}

#define TS 132  // padded LDS stride for the fp32 final kernel

__global__ __launch_bounds__(256) void mps_final(const float* __restrict__ res,
                                                 const float* __restrict__ middle,
                                                 float* __restrict__ out) {
  __shared__ float lA[128 * TS];  // R = res[1][b]
  __shared__ float lB[128 * TS];  // L = res[0][b]
  __shared__ float red[4][10];

  const int tid = threadIdx.x;
  const int b   = blockIdx.x;
  const float* Rg = res + (size_t)(128 + b) * 16384;
  const float* Lg = res + (size_t)b * 16384;

#pragma unroll
  for (int it = 0; it < 16; ++it) {
    int g = it * 256 + tid;
    int row = g >> 5, col = (g & 31) * 4;
    *(float4*)&lA[row * TS + col] = *(const float4*)(Rg + g * 4);
    *(float4*)&lB[row * TS + col] = *(const float4*)(Lg + g * 4);
  }
  __syncthreads();

  const int ty = tid >> 4, tx = tid & 15;
  const int k0 = ty * 8, j0 = tx * 8;

  float ct[8][8];
#pragma unroll
  for (int i = 0; i < 8; ++i)
#pragma unroll
    for (int j = 0; j < 8; ++j) ct[i][j] = 0.f;

  for (int k = 0; k < 128; k += 4) {
    float4 a[8];
#pragma unroll
    for (int i = 0; i < 8; ++i)
      a[i] = *(const float4*)&lA[(k0 + i) * TS + k];
    float4 b0[4], b1[4];
#pragma unroll
    for (int kk = 0; kk < 4; ++kk) {
      b0[kk] = *(const float4*)&lB[(k + kk) * TS + j0];
      b1[kk] = *(const float4*)&lB[(k + kk) * TS + j0 + 4];
    }
#pragma unroll
    for (int i = 0; i < 8; ++i) {
      const float av[4] = {a[i].x, a[i].y, a[i].z, a[i].w};
#pragma unroll
      for (int kk = 0; kk < 4; ++kk) {
        const float aa = av[kk];
        ct[i][0] = fmaf(aa, b0[kk].x, ct[i][0]);
        ct[i][1] = fmaf(aa, b0[kk].y, ct[i][1]);
        ct[i][2] = fmaf(aa, b0[kk].z, ct[i][2]);
        ct[i][3] = fmaf(aa, b0[kk].w, ct[i][3]);
        ct[i][4] = fmaf(aa, b1[kk].x, ct[i][4]);
        ct[i][5] = fmaf(aa, b1[kk].y, ct[i][5]);
        ct[i][6] = fmaf(aa, b1[kk].z, ct[i][6]);
        ct[i][7] = fmaf(aa, b1[kk].w, ct[i][7]);
      }
    }
  }
  // ct[i][jj] = (R@L)[k0+i][j0+jj];  out[b,c] = sum mid[c][j][k] * P[k][j]
#pragma unroll
  for (int cc = 0; cc < 10; ++cc) {
    const float* m = middle + cc * 16384;
    float accv = 0.f;
#pragma unroll
    for (int jj = 0; jj < 8; ++jj) {
      const float* mr = m + (j0 + jj) * 128 + k0;
      float4 m0 = *(const float4*)(mr);
      float4 m1 = *(const float4*)(mr + 4);
      accv += m0.x * ct[0][jj] + m0.y * ct[1][jj] + m0.z * ct[2][jj] + m0.w * ct[3][jj];
      accv += m1.x * ct[4][jj] + m1.y * ct[5][jj] + m1.z * ct[6][jj] + m1.w * ct[7][jj];
    }
    float v = accv;
#pragma unroll
    for (int off = 32; off > 0; off >>= 1) v += __shfl_down(v, off);
    if ((tid & 63) == 0) red[tid >> 6][cc] = v;
  }
  __syncthreads();
  if (tid < 10)
    out[b * 10 + tid] = red[0][tid] + red[1][tid] + red[2][tid] + red[3][tid];
}

extern "C" void kernel_launch(void* const* d_in, const int* in_sizes, int n_in,
                              void* d_out, int out_size, void* d_ws, size_t ws_size,
                              hipStream_t stream) {
  const float* inputs = (const float*)d_in[0];  // (128, 64, 2)
  const float* left   = (const float*)d_in[1];  // (2, 32, 128, 128)
  const float* right  = (const float*)d_in[2];  // (2, 32, 128, 128)
  const float* middle = (const float*)d_in[3];  // (10, 128, 128)
  float* out = (float*)d_out;                   // (128, 10)

  float*  res = (float*)d_ws;                                   // 16 MB
  ushort* Dt  = (ushort*)((char*)d_ws + (size_t)16 * 1024 * 1024);  // 4 MB

  make_dt<<<1024, 256, 0, stream>>>(left, right, Dt);
  mps_chain_mfma<<<256, 256, 0, stream>>>(inputs, left, right, Dt, res);
  mps_final<<<128, 256, 0, stream>>>(res, middle, out);
}

// Round 4
// 178.901 us; speedup vs baseline: 2.8755x; 1.2608x over previous
//
#include <hip/hip_runtime.h>

// MPS layer, MFMA single-pass version.
// Math: M_s = x0*W0[s] + x1*W1[s] = s01*I + x0*D0[s] + x1*D1[s], D = W - I.
// Maintain T = (M_0...M_s)^T in MFMA accumulators:
//   T_new = s01*T (exact fp32 VALU) + D0^T*(x0*T)_bf16 + D1^T*(x1*T)_bf16.
// Single bf16 pass: rounding of T enters only via x*D^T*eps, D ~ 0.01 scale
// -> per-step rel err ~2e-4, accumulated ~2e-3; threshold margin ~3-5x.
//
// Layouts (v_mfma_f32_32x32x16_bf16, validated in round 3, absmax 0.5):
//   A-operand: lane l holds row m=l&31, k = 8*(l>>5)+j (j=0..7)
//   B-operand: lane l holds col n=l&31, k = 8*(l>>5)+j
//   C/D:       lane l holds col  c=l&31, row = (reg&3)+8*(reg>>2)+4*(l>>5)
// acc->B conversion: per k-half q: v_permlane32_swap_b32 on reg pairs
// (q*8+r, q*8+4+r); then slot q*8+j = T[32t+16q+8*hi+j][col].
//
// Staging: global_load_lds width=16 (linear LDS chunk = wave base + lane*16B),
// issued at step start for s+1 into buf^1; end-of-step __syncthreads drains.
//
// ws: res[2][128][128][128] f32 (16MB) | Dt (4MB bf16 fragment-major)
// Dt[mat][ (ks*4+mt)*512 + l*8 + j ] = W[mat][16ks+8(l>>5)+j][32mt+(l&31)] - I

typedef __attribute__((ext_vector_type(8))) short short8v;
typedef __attribute__((ext_vector_type(16))) float f32x16;

__device__ __forceinline__ unsigned cvt_pk_bf16(float lo, float hi) {
  unsigned r;
  asm("v_cvt_pk_bf16_f32 %0, %1, %2" : "=v"(r) : "v"(lo), "v"(hi));
  return r;
}

#define GLOAD_LDS16(g, l)                                          \
  __builtin_amdgcn_global_load_lds(                                \
      (const __attribute__((address_space(1))) void*)(g),          \
      (__attribute__((address_space(3))) void*)(l), 16, 0, 0)

// One block per matrix (128 total): coalesced stage -> LDS -> coalesced
// fragment writes. Replaces the strided-read make_dt (suspected ~70us).
__global__ __launch_bounds__(256) void make_dt(const float* __restrict__ left,
                                               const float* __restrict__ right,
                                               ushort* __restrict__ Dt) {
  __shared__ float lw[128 * 132];
  const int tid = threadIdx.x;
  const int mat = blockIdx.x;  // side*64 + p*32 + s
  const float* W = (mat >= 64 ? right : left) + (size_t)(mat & 63) * 16384;

#pragma unroll
  for (int it = 0; it < 16; ++it) {
    int g = it * 256 + tid;  // float4 index
    float4 v = *(const float4*)(W + g * 4);
    int row = g >> 5, col = (g & 31) * 4;
    *(float4*)&lw[row * 132 + col] = v;
  }
  __syncthreads();

#pragma unroll
  for (int ff = 0; ff < 8; ++ff) {
    int f = ff * 256 + tid;  // fragment slot 0..2047
    int l = f & 63, mt = (f >> 6) & 3, ks = f >> 8;
    int m = 32 * mt + (l & 31), kb = 16 * ks + 8 * (l >> 5);
    float v[8];
#pragma unroll
    for (int j = 0; j < 8; ++j)
      v[j] = lw[(kb + j) * 132 + m] - ((kb + j == m) ? 1.0f : 0.0f);
    uint4 o;
    o.x = cvt_pk_bf16(v[0], v[1]);
    o.y = cvt_pk_bf16(v[2], v[3]);
    o.z = cvt_pk_bf16(v[4], v[5]);
    o.w = cvt_pk_bf16(v[6], v[7]);
    *(uint4*)(Dt + (size_t)mat * 16384 + (size_t)f * 8) = o;
  }
}

__global__ __launch_bounds__(256, 1) void mps_chain_mfma(
    const float* __restrict__ inp, const float* __restrict__ left,
    const float* __restrict__ right, const ushort* __restrict__ Dt,
    float* __restrict__ res) {
  __shared__ ushort ldsD[2][32768];  // [buf][p*16384 + (ks*4+mt)*512 + lane*8]
  __shared__ float xs[64];

  const int tid  = threadIdx.x;
  const int half = blockIdx.x >> 7;
  const int b    = blockIdx.x & 127;
  const int lane = tid & 63;
  const int w    = tid >> 6;  // wave owns T cols 32w..32w+31
  const int c    = lane & 31;
  const int hi   = lane >> 5;
  const int cg   = 32 * w + c;
  const int wofs = w * 512;  // ushort offset of this wave's slice in a chunk

  if (tid < 64) xs[tid] = inp[b * 128 + half * 64 + tid];

  const ushort* DtH = Dt + (size_t)(half * 2) * 32 * 16384;  // p=0 slab

  __syncthreads();  // xs ready

  // issue stage of s=1 into buf0 (latency hides under T0 init)
#pragma unroll
  for (int p = 0; p < 2; ++p) {
    const ushort* gp = DtH + (size_t)(p * 32 + 1) * 16384;
#pragma unroll
    for (int i = 0; i < 8; ++i)
      GLOAD_LDS16(gp + i * 2048 + wofs + lane * 8,
                  &ldsD[0][p * 16384 + i * 2048 + wofs]);
  }

  f32x16 acc[4];  // T: acc[t] = rows 32t..32t+31, col cg

  // T_0 = M_0^T from W (fp32): T0[row][cg] = M0[cg][row]
  {
    const float* Wg = half ? right : left;
    const float x0 = xs[0], x1 = xs[1];
#pragma unroll
    for (int t = 0; t < 4; ++t)
#pragma unroll
      for (int g = 0; g < 4; ++g) {
        const int row = 32 * t + 8 * g + 4 * hi;
        const float4 w0 = *(const float4*)(Wg + cg * 128 + row);
        const float4 w1 = *(const float4*)(Wg + 32 * 16384 + cg * 128 + row);
        acc[t][4 * g + 0] = x0 * w0.x + x1 * w1.x;
        acc[t][4 * g + 1] = x0 * w0.y + x1 * w1.y;
        acc[t][4 * g + 2] = x0 * w0.z + x1 * w1.z;
        acc[t][4 * g + 3] = x0 * w0.w + x1 * w1.w;
      }
  }

  __syncthreads();  // drains vmcnt -> buf0 staged & visible

  int cur = 0;
  for (int s = 1; s < 32; ++s) {
    const float x0 = xs[2 * s], x1 = xs[2 * s + 1];
    const float s01 = x0 + x1;

    // issue prefetch of step s+1 into buf^1 (drained by end-of-step barrier)
    if (s < 31) {
#pragma unroll
      for (int p = 0; p < 2; ++p) {
        const ushort* gp = DtH + (size_t)(p * 32 + s + 1) * 16384;
#pragma unroll
        for (int i = 0; i < 8; ++i)
          GLOAD_LDS16(gp + i * 2048 + wofs + lane * 8,
                      &ldsD[cur ^ 1][p * 16384 + i * 2048 + wofs]);
      }
    }

    // identity part (exact fp32) before acc is permuted in-place
    f32x16 tn[4];
#pragma unroll
    for (int t = 0; t < 4; ++t)
#pragma unroll
      for (int r = 0; r < 16; ++r) tn[t][r] = s01 * acc[t][r];

    // per k-slice: convert T -> scaled bf16 B-frags, then 8 MFMAs
#pragma unroll
    for (int ks = 0; ks < 8; ++ks) {
      const int t = ks >> 1, q = ks & 1;
#pragma unroll
      for (int r = 0; r < 4; ++r) {
        float a  = acc[t][q * 8 + r];
        float b2 = acc[t][q * 8 + 4 + r];
        asm volatile("v_permlane32_swap_b32 %0, %1" : "+v"(a), "+v"(b2));
        acc[t][q * 8 + r]     = a;   // T[32t+16q+8*hi+r][cg]
        acc[t][q * 8 + 4 + r] = b2;  // T[32t+16q+8*hi+4+r][cg]
      }
      uint4 p0, p1;
      {
        const float* v = (const float*)&acc[t] + q * 8;
        p0.x = cvt_pk_bf16(x0 * v[0], x0 * v[1]);
        p0.y = cvt_pk_bf16(x0 * v[2], x0 * v[3]);
        p0.z = cvt_pk_bf16(x0 * v[4], x0 * v[5]);
        p0.w = cvt_pk_bf16(x0 * v[6], x0 * v[7]);
        p1.x = cvt_pk_bf16(x1 * v[0], x1 * v[1]);
        p1.y = cvt_pk_bf16(x1 * v[2], x1 * v[3]);
        p1.z = cvt_pk_bf16(x1 * v[4], x1 * v[5]);
        p1.w = cvt_pk_bf16(x1 * v[6], x1 * v[7]);
      }
      const short8v y0 = __builtin_bit_cast(short8v, p0);
      const short8v y1 = __builtin_bit_cast(short8v, p1);
#pragma unroll
      for (int mt = 0; mt < 4; ++mt) {
        short8v d0 = *(const short8v*)&ldsD[cur][(ks * 4 + mt) * 512 + lane * 8];
        short8v d1 = *(const short8v*)&ldsD[cur][16384 + (ks * 4 + mt) * 512 + lane * 8];
        tn[mt] = __builtin_amdgcn_mfma_f32_32x32x16_bf16(d0, y0, tn[mt], 0, 0, 0);
        tn[mt] = __builtin_amdgcn_mfma_f32_32x32x16_bf16(d1, y1, tn[mt], 0, 0, 0);
      }
    }

#pragma unroll
    for (int t = 0; t < 4; ++t) acc[t] = tn[t];
    __syncthreads();  // buf[cur] reads done; buf[cur^1] staging drained
    cur ^= 1;
  }

  // T[r][cg] = L[cg][r]: store row cg row-major (same layout as fp32 version)
  float* O = res + (size_t)(half * 128 + b) * 16384;
#pragma unroll
  for (int t = 0; t < 4; ++t)
#pragma unroll
    for (int g = 0; g < 4; ++g) {
      const int row = 32 * t + 8 * g + 4 * hi;
      float4 o = {acc[t][4 * g + 0], acc[t][4 * g + 1], acc[t][4 * g + 2],
                  acc[t][4 * g + 3]};
      *(float4*)(O + cg * 128 + row) = o;
    }
}

#define TS 132  // padded LDS stride for the fp32 final kernel

__global__ __launch_bounds__(256) void mps_final(const float* __restrict__ res,
                                                 const float* __restrict__ middle,
                                                 float* __restrict__ out) {
  __shared__ float lA[128 * TS];  // R = res[1][b]
  __shared__ float lB[128 * TS];  // L = res[0][b]
  __shared__ float red[4][10];

  const int tid = threadIdx.x;
  const int b   = blockIdx.x;
  const float* Rg = res + (size_t)(128 + b) * 16384;
  const float* Lg = res + (size_t)b * 16384;

#pragma unroll
  for (int it = 0; it < 16; ++it) {
    int g = it * 256 + tid;
    int row = g >> 5, col = (g & 31) * 4;
    *(float4*)&lA[row * TS + col] = *(const float4*)(Rg + g * 4);
    *(float4*)&lB[row * TS + col] = *(const float4*)(Lg + g * 4);
  }
  __syncthreads();

  const int ty = tid >> 4, tx = tid & 15;
  const int k0 = ty * 8, j0 = tx * 8;

  float ct[8][8];
#pragma unroll
  for (int i = 0; i < 8; ++i)
#pragma unroll
    for (int j = 0; j < 8; ++j) ct[i][j] = 0.f;

  for (int k = 0; k < 128; k += 4) {
    float4 a[8];
#pragma unroll
    for (int i = 0; i < 8; ++i)
      a[i] = *(const float4*)&lA[(k0 + i) * TS + k];
    float4 b0[4], b1[4];
#pragma unroll
    for (int kk = 0; kk < 4; ++kk) {
      b0[kk] = *(const float4*)&lB[(k + kk) * TS + j0];
      b1[kk] = *(const float4*)&lB[(k + kk) * TS + j0 + 4];
    }
#pragma unroll
    for (int i = 0; i < 8; ++i) {
      const float av[4] = {a[i].x, a[i].y, a[i].z, a[i].w};
#pragma unroll
      for (int kk = 0; kk < 4; ++kk) {
        const float aa = av[kk];
        ct[i][0] = fmaf(aa, b0[kk].x, ct[i][0]);
        ct[i][1] = fmaf(aa, b0[kk].y, ct[i][1]);
        ct[i][2] = fmaf(aa, b0[kk].z, ct[i][2]);
        ct[i][3] = fmaf(aa, b0[kk].w, ct[i][3]);
        ct[i][4] = fmaf(aa, b1[kk].x, ct[i][4]);
        ct[i][5] = fmaf(aa, b1[kk].y, ct[i][5]);
        ct[i][6] = fmaf(aa, b1[kk].z, ct[i][6]);
        ct[i][7] = fmaf(aa, b1[kk].w, ct[i][7]);
      }
    }
  }
  // ct[i][jj] = (R@L)[k0+i][j0+jj];  out[b,c] = sum mid[c][j][k] * P[k][j]
#pragma unroll
  for (int cc = 0; cc < 10; ++cc) {
    const float* m = middle + cc * 16384;
    float accv = 0.f;
#pragma unroll
    for (int jj = 0; jj < 8; ++jj) {
      const float* mr = m + (j0 + jj) * 128 + k0;
      float4 m0 = *(const float4*)(mr);
      float4 m1 = *(const float4*)(mr + 4);
      accv += m0.x * ct[0][jj] + m0.y * ct[1][jj] + m0.z * ct[2][jj] + m0.w * ct[3][jj];
      accv += m1.x * ct[4][jj] + m1.y * ct[5][jj] + m1.z * ct[6][jj] + m1.w * ct[7][jj];
    }
    float v = accv;
#pragma unroll
    for (int off = 32; off > 0; off >>= 1) v += __shfl_down(v, off);
    if ((tid & 63) == 0) red[tid >> 6][cc] = v;
  }
  __syncthreads();
  if (tid < 10)
    out[b * 10 + tid] = red[0][tid] + red[1][tid] + red[2][tid] + red[3][tid];
}

extern "C" void kernel_launch(void* const* d_in, const int* in_sizes, int n_in,
                              void* d_out, int out_size, void* d_ws, size_t ws_size,
                              hipStream_t stream) {
  const float* inputs = (const float*)d_in[0];  // (128, 64, 2)
  const float* left   = (const float*)d_in[1];  // (2, 32, 128, 128)
  const float* right  = (const float*)d_in[2];  // (2, 32, 128, 128)
  const float* middle = (const float*)d_in[3];  // (10, 128, 128)
  float* out = (float*)d_out;                   // (128, 10)

  float*  res = (float*)d_ws;                                       // 16 MB
  ushort* Dt  = (ushort*)((char*)d_ws + (size_t)16 * 1024 * 1024);  // 4 MB

  make_dt<<<128, 256, 0, stream>>>(left, right, Dt);
  mps_chain_mfma<<<256, 256, 0, stream>>>(inputs, left, right, Dt, res);
  mps_final<<<128, 256, 0, stream>>>(res, middle, out);
}